// Round 4
// baseline (1015.623 us; speedup 1.0000x reference)
//
#include <hip/hip_runtime.h>

// ---------------------------------------------------------------------------
// GFGCN round 4.
// S-GEMM: register-direct 32x32x16 bf16 MFMA, compile-time K-chunk (full
// unroll -> compiler software-pipelines the global loads), split-K=16.
// Layouts (guide §3, m74/m101-verified C/D for 32x32; A/B mirror 16x16):
//   A-frag : lane holds A[m = lane&31][k = (lane>>5)*8 + j]  (16 B/lane)
//   B-frag : lane holds B[k = (lane>>5)*8 + j][n = lane&31]  == Bt[n][k..k+7]
//   C/D    : col = lane&31, row = (reg&3) + 8*(reg>>2) + 4*(lane>>5)
//            -> per reg-group g: rows g*8 + (lane>>5)*4 + 0..3 (contiguous 4)
// W-GEMMs: 16x16x32 register-direct (m89/m91-verified layouts).
// ---------------------------------------------------------------------------

typedef __attribute__((ext_vector_type(4)))  float  f32x4;
typedef __attribute__((ext_vector_type(16))) float  f32x16;
typedef __attribute__((ext_vector_type(8)))  __bf16 bf16x8;
typedef __attribute__((ext_vector_type(4)))  __bf16 bf16x4;

__global__ void cvt_f32_bf16(const float4* __restrict__ in,
                             bf16x4* __restrict__ out, int n4) {
    int i  = blockIdx.x * blockDim.x + threadIdx.x;
    int st = gridDim.x * blockDim.x;
    for (; i < n4; i += st) {
        float4 v = in[i];
        bf16x4 o;
        o[0] = (__bf16)v.x; o[1] = (__bf16)v.y;
        o[2] = (__bf16)v.z; o[3] = (__bf16)v.w;
        out[i] = o;
    }
}

__global__ void cvt_transpose(const float* __restrict__ W,
                              __bf16* __restrict__ Wt, int Kd, int Md) {
    int i = blockIdx.x * blockDim.x + threadIdx.x;
    if (i < Kd * Md) {
        int k = i / Md, m = i % Md;
        Wt[(size_t)m * Kd + k] = (__bf16)W[i];
    }
}

// ---------------------------------------------------------------------------
// S-GEMM: C[M,N] partials = A[M,K] @ Bt[N,K]^T over K-chunk KCH.
// Block = 4 waves stacked in M (128 rows); wave = 32 rows x 64 cols (NF=2).
// grid: x = m-tile (M/128), y = n-tile (N/64), z = split (K/KCH).
// Output: fp32 partials, t-layout P[z][col][row], rows contiguous (f32x4).
// ---------------------------------------------------------------------------
template<int KCH>
__global__ __launch_bounds__(256, 4)
void sgemm32(const __bf16* __restrict__ A, const __bf16* __restrict__ Bt,
             float* __restrict__ P, int K, int Mtot, int Ntot)
{
    const int lane = threadIdx.x & 63;
    const int w    = threadIdx.x >> 6;
    const int l31  = lane & 31;
    const int half = lane >> 5;

    const int m_base = blockIdx.x * 128 + w * 32;
    const int n_base = blockIdx.y * 64;
    const int kstart = blockIdx.z * KCH;

    const __bf16* Ap  = A  + (size_t)(m_base + l31) * K + kstart + half * 8;
    const __bf16* Bp0 = Bt + (size_t)(n_base      + l31) * K + kstart + half * 8;
    const __bf16* Bp1 = Bt + (size_t)(n_base + 32 + l31) * K + kstart + half * 8;

    f32x16 acc0 = {}, acc1 = {};

    #pragma unroll
    for (int ks = 0; ks < KCH; ks += 16) {
        bf16x8 a  = *(const bf16x8*)(Ap  + ks);
        bf16x8 b0 = *(const bf16x8*)(Bp0 + ks);
        bf16x8 b1 = *(const bf16x8*)(Bp1 + ks);
        acc0 = __builtin_amdgcn_mfma_f32_32x32x16_bf16(a, b0, acc0, 0, 0, 0);
        acc1 = __builtin_amdgcn_mfma_f32_32x32x16_bf16(a, b1, acc1, 0, 0, 0);
    }

    float* Pz = P + (size_t)blockIdx.z * Mtot * Ntot;
    #pragma unroll
    for (int g = 0; g < 4; g++) {
        const int row = m_base + g * 8 + half * 4;
        const int c0  = n_base + l31;
        f32x4 v0 = {acc0[g*4+0], acc0[g*4+1], acc0[g*4+2], acc0[g*4+3]};
        f32x4 v1 = {acc1[g*4+0], acc1[g*4+1], acc1[g*4+2], acc1[g*4+3]};
        *(f32x4*)(Pz + (size_t)c0        * Mtot + row) = v0;
        *(f32x4*)(Pz + (size_t)(c0 + 32) * Mtot + row) = v1;
    }
}

// ---------------------------------------------------------------------------
// Small W-GEMM (16x16x32): block = 4 waves in M; wave = 16 x (16*NF).
// OUT: bf16 row-major out[row*Ntot + col] (t-layout for downstream).
// ---------------------------------------------------------------------------
template<int NF>
__global__ __launch_bounds__(256, 4)
void gemm_w(const __bf16* __restrict__ A, const __bf16* __restrict__ Bt,
            __bf16* __restrict__ O, int K, int Ntot)
{
    const int lane = threadIdx.x & 63;
    const int w    = threadIdx.x >> 6;
    const int l15  = lane & 15;
    const int quad = lane >> 4;

    const int m_base = blockIdx.x * 64 + w * 16;
    const int n_base = blockIdx.y * (16 * NF);

    const __bf16* Ap = A + (size_t)(m_base + l15) * K + quad * 8;
    const __bf16* Bp[NF];
    #pragma unroll
    for (int nf = 0; nf < NF; nf++)
        Bp[nf] = Bt + (size_t)(n_base + nf * 16 + l15) * K + quad * 8;

    f32x4 acc[NF];
    #pragma unroll
    for (int nf = 0; nf < NF; nf++) acc[nf] = (f32x4){0.f, 0.f, 0.f, 0.f};

    for (int ks = 0; ks < K; ks += 32) {
        bf16x8 a = *(const bf16x8*)(Ap + ks);
        #pragma unroll
        for (int nf = 0; nf < NF; nf++) {
            bf16x8 b = *(const bf16x8*)(Bp[nf] + ks);
            acc[nf] = __builtin_amdgcn_mfma_f32_16x16x32_bf16(a, b, acc[nf], 0, 0, 0);
        }
    }

    #pragma unroll
    for (int nf = 0; nf < NF; nf++) {
        const int col  = n_base + nf * 16 + l15;
        const int rowb = m_base + quad * 4;
        #pragma unroll
        for (int r = 0; r < 4; r++)
            O[(size_t)(rowb + r) * Ntot + col] = (__bf16)acc[nf][r];
    }
}

// ---- sum SP split-partials -> bf16 t-layout Y[f][node] ----
template<int SP>
__global__ void reduce_partials(const float* __restrict__ P,
                                __bf16* __restrict__ Y, int total4, int MN) {
    int i = blockIdx.x * blockDim.x + threadIdx.x;
    if (i >= total4) return;
    size_t base = (size_t)i * 4;
    float4 s = *(const float4*)(P + base);
    #pragma unroll
    for (int sp = 1; sp < SP; sp++) {
        float4 v = *(const float4*)(P + (size_t)sp * MN + base);
        s.x += v.x; s.y += v.y; s.z += v.z; s.w += v.w;
    }
    bf16x4 o; o[0] = (__bf16)s.x; o[1] = (__bf16)s.y;
    o[2] = (__bf16)s.z; o[3] = (__bf16)s.w;
    *(bf16x4*)(Y + base) = o;
}

// ---- combine: out[node][f] = act(h0*Y0 + h1*Y1 + h2*sum(P) + b[f]) ----
template<int SP, int RELU, int F32OUT>
__global__ void combine_out(const float* __restrict__ P,
                            const __bf16* __restrict__ Y0t,
                            const __bf16* __restrict__ Y1t,
                            const float* __restrict__ h,
                            const float* __restrict__ bias,
                            void* __restrict__ outp, int F) {
    const int i = blockIdx.x * blockDim.x + threadIdx.x;  // (f, node4)
    if (i >= F * 2048) return;
    const int f  = i >> 11;
    const int n4 = i & 2047;
    const size_t base = (size_t)f * 8192 + (size_t)n4 * 4;
    const int MN = F * 8192;

    float4 s = *(const float4*)(P + base);
    #pragma unroll
    for (int sp = 1; sp < SP; sp++) {
        float4 v = *(const float4*)(P + (size_t)sp * MN + base);
        s.x += v.x; s.y += v.y; s.z += v.z; s.w += v.w;
    }
    bf16x4 y0 = *(const bf16x4*)(Y0t + base);
    bf16x4 y1 = *(const bf16x4*)(Y1t + base);
    const float h0 = h[0], h1 = h[1], h2 = h[2], bb = bias[f];

    float v[4] = {s.x, s.y, s.z, s.w};
    #pragma unroll
    for (int r = 0; r < 4; r++) {
        float x = h0 * (float)y0[r] + h1 * (float)y1[r] + h2 * v[r] + bb;
        if (RELU) x = fmaxf(x, 0.0f);
        v[r] = x;
    }
    const int node = n4 * 4;
    if (F32OUT) {
        float* O = (float*)outp;
        #pragma unroll
        for (int r = 0; r < 4; r++) O[(size_t)(node + r) * F + f] = v[r];
    } else {
        __bf16* O = (__bf16*)outp;
        #pragma unroll
        for (int r = 0; r < 4; r++) O[(size_t)(node + r) * F + f] = (__bf16)v[r];
    }
}

extern "C" void kernel_launch(void* const* d_in, const int* in_sizes, int n_in,
                              void* d_out, int out_size, void* d_ws, size_t ws_size,
                              hipStream_t stream) {
    const float* S  = (const float*)d_in[0];
    const float* X  = (const float*)d_in[1];
    const float* W1 = (const float*)d_in[2];
    const float* h1 = (const float*)d_in[3];
    const float* b1 = (const float*)d_in[4];
    const float* W2 = (const float*)d_in[5];
    const float* h2 = (const float*)d_in[6];
    const float* b2 = (const float*)d_in[7];
    const float* W3 = (const float*)d_in[8];
    const float* h3 = (const float*)d_in[9];
    const float* b3 = (const float*)d_in[10];
    float* out = (float*)d_out;

    const int Nn = 8192, IN = 512, HID = 128, OUT = 64;
    constexpr int SP  = 16;
    constexpr int KCH = 512;          // 8192 / SP

    char* ws = (char*)d_ws;
    size_t off = 0;
    auto carve = [&](size_t bytes) -> void* {
        void* p = ws + off;
        off += (bytes + 255) & ~(size_t)255;
        return p;
    };
    __bf16* Sb  = (__bf16*)carve((size_t)Nn * Nn  * 2);   // 134.2 MB
    __bf16* Xb  = (__bf16*)carve((size_t)Nn * IN  * 2);   // 8.4 MB
    __bf16* W1t = (__bf16*)carve((size_t)IN  * HID * 2);
    __bf16* W2t = (__bf16*)carve((size_t)HID * HID * 2);
    __bf16* W3t = (__bf16*)carve((size_t)HID * OUT * 2);
    __bf16* Y0t = (__bf16*)carve((size_t)HID * Nn * 2);   // [F][8192]
    __bf16* Y1t = (__bf16*)carve((size_t)HID * Nn * 2);
    __bf16* Act = (__bf16*)carve((size_t)Nn * HID * 2);   // [node][F] t-layout
    float*  P   = (float*)carve((size_t)SP * HID * Nn * 4); // 64 MB

    // ---- converts ----
    {
        int n4 = Nn * Nn / 4;
        cvt_f32_bf16<<<dim3((n4 + 255) / 256), dim3(256), 0, stream>>>(
            (const float4*)S, (bf16x4*)Sb, n4);
        n4 = Nn * IN / 4;
        cvt_f32_bf16<<<dim3((n4 + 255) / 256), dim3(256), 0, stream>>>(
            (const float4*)X, (bf16x4*)Xb, n4);
    }
    cvt_transpose<<<dim3((IN * HID + 255) / 256), dim3(256), 0, stream>>>(W1, W1t, IN, HID);
    cvt_transpose<<<dim3((HID * HID + 255) / 256), dim3(256), 0, stream>>>(W2, W2t, HID, HID);
    cvt_transpose<<<dim3((HID * OUT + 255) / 256), dim3(256), 0, stream>>>(W3, W3t, HID, OUT);

    // S-GEMM: partials P[s][f][node]; A=Sb (ld 8192), B=Yt[f][8192]
    auto sgemm = [&](const __bf16* Bt, int F) {
        sgemm32<KCH><<<dim3(Nn / 128, F / 64, SP), dim3(256), 0, stream>>>(
            Sb, Bt, P, Nn, Nn, F);
    };
    auto reduceY = [&](__bf16* Y, int F) {
        int t4 = F * 2048;
        reduce_partials<SP><<<dim3((t4 + 255) / 256), dim3(256), 0, stream>>>(
            P, Y, t4, F * Nn);
    };

    // ---- layer 1 ----
    gemm_w<4><<<dim3(HID / 64, Nn / 64), dim3(256), 0, stream>>>(
        W1t, Xb, Y0t, IN, Nn);                    // Y0t = W1t @ Xb^T
    sgemm(Y0t, HID);
    reduceY(Y1t, HID);
    sgemm(Y1t, HID);
    combine_out<SP, 1, 0><<<dim3(HID * 2048 / 256), dim3(256), 0, stream>>>(
        P, Y0t, Y1t, h1, b1, Act, HID);

    // ---- layer 2 ----
    gemm_w<4><<<dim3(HID / 64, Nn / 64), dim3(256), 0, stream>>>(
        W2t, Act, Y0t, HID, Nn);
    sgemm(Y0t, HID);
    reduceY(Y1t, HID);
    sgemm(Y1t, HID);
    combine_out<SP, 1, 0><<<dim3(HID * 2048 / 256), dim3(256), 0, stream>>>(
        P, Y0t, Y1t, h2, b2, Act, HID);

    // ---- layer 3 (F=64, fp32 out, no relu) ----
    gemm_w<4><<<dim3(OUT / 64, Nn / 64), dim3(256), 0, stream>>>(
        W3t, Act, Y0t, HID, Nn);
    sgemm(Y0t, OUT);
    reduceY(Y1t, OUT);
    sgemm(Y1t, OUT);
    combine_out<SP, 0, 1><<<dim3(OUT * 2048 / 256), dim3(256), 0, stream>>>(
        P, Y0t, Y1t, h3, b3, out, OUT);

    (void)in_sizes; (void)n_in; (void)out_size; (void)ws_size;
}